// Round 11
// baseline (196.904 us; speedup 1.0000x reference)
//
#include <hip/hip_runtime.h>
#include <math.h>

#define NA 360
#define NP 512
#define NB 16
#define IMG 512
#define PS 514               // p' in [0,513]; point p' holds taps (s[p'-1], s[p'])
#define ACH 8                // angles per LDS chunk
#define NCH (NA / ACH)       // 45 chunks
#define NPT 32               // LDS points per angle (span <= 25 incl. margins)

typedef unsigned int uint32;
typedef __fp16 half2 __attribute__((ext_vector_type(2)));   // builtin V2h type

static __device__ __forceinline__ half2 u2h(uint32 u) {
    union { uint32 u; half2 h; } v; v.u = u; return v.h;
}
static __device__ __forceinline__ uint32 pk(float a, float b) {
    union { half2 h; uint32 u; } v;
    v.h = __builtin_amdgcn_cvt_pkrtz(a, b);
    return v.u;
}

#if __has_builtin(__builtin_amdgcn_fdot2)
static __device__ __forceinline__ float dot2(half2 w, half2 v, float acc) {
    return __builtin_amdgcn_fdot2(w, v, acc, false);
}
#else
static __device__ __forceinline__ float dot2(half2 w, half2 v, float acc) {
    return fmaf((float)w.x, (float)v.x, fmaf((float)w.y, (float)v.y, acc));
}
#endif

// tab[a] = {c'=cos/dp, s'=sin/dp, off=-pos0/dp, (|c'|+|s'|)*7.5 (block half-span)}
static __device__ __forceinline__ void write_tab(const float* thetas,
                                                 const float* positions,
                                                 float4* tab, int a) {
    double th = (double)thetas[a];
    double p0 = (double)positions[0];
    double dp = (double)positions[1] - p0;
    double c = cos(th) / dp, s = sin(th) / dp;
    tab[a] = make_float4((float)c, (float)s, (float)(-p0 / dp),
                         (float)((fabs(c) + fabs(s)) * 7.5));
}

// Staging: [b][a][p] f32 -> 4 planes, plane k: [a][p'] uint4 = f16 tap-pairs
// for batches 4k..4k+3. One thread per (plane, point): 4x the TLP of the old
// version (stage was latency-bound at ~3 waves/CU).
__global__ void stage(const float* __restrict__ sino,
                      const float* __restrict__ thetas,
                      const float* __restrict__ positions,
                      float4* __restrict__ tab,
                      uint4* __restrict__ st) {
    if (blockIdx.x == gridDim.x - 1) {
        int a = threadIdx.x;
        if (a < NA) write_tab(thetas, positions, tab, a);
        int a2 = threadIdx.x + 256;
        if (a2 < NA) write_tab(thetas, positions, tab, a2);
        return;
    }
    int idx = blockIdx.x * 256 + threadIdx.x;   // idx = (k*NA + a)*PS + p'
    if (idx >= 4 * NA * PS) return;
    const int k   = idx / (NA * PS);
    const int rem = idx - k * (NA * PS);
    const int a   = rem / PS;
    const int pp  = rem - a * PS;
    const int p0  = pp - 1;
    uint32 r[4];
#pragma unroll
    for (int i = 0; i < 4; ++i) {
        const float* row = sino + ((size_t)(4 * k + i) * NA + a) * NP;
        float f0 = (p0 >= 0 && p0 < NP) ? row[p0] : 0.0f;
        float f1 = (pp < NP) ? row[pp] : 0.0f;
        r[i] = pk(f0, f1);
    }
    st[idx] = make_uint4(r[0], r[1], r[2], r[3]);
}

// Window start with 1-point lower margin against fp rounding (round-8 lesson).
static __device__ __forceinline__ int pmin_of(float tc, float tw) {
    float fmn = fminf(fmaxf(tc - tw, -1.0f), 512.0f);
    return min(max((int)floorf(fmn) - 1, 0), PS - NPT);
}

// Hybrid pipe split: batches 0..7 (planes 0,1) via LDS window DMA
// (global_load_lds, 2 ds_read_b128/angle); batches 8..15 (planes 2,3) via
// direct global gather with distance-2 ping-pong prefetch in NAMED registers
// (arrays across barriers -> scratch demotion, round-9 lesson).
__launch_bounds__(256)
__global__ void backproject(const uint4* __restrict__ st,
                            const float4* __restrict__ tab,
                            float* __restrict__ out) {
    __shared__ uint4 buf[2][ACH * 2 * NPT];     // 2 x 8 KB, [al][q][pt]
    __shared__ int pm_lds[NA];                  // 1.44 KB
    const int tid = threadIdx.y * 16 + threadIdx.x;
    const int x = blockIdx.x * 16 + threadIdx.x;
    const int y = blockIdx.y * 16 + threadIdx.y;
    const float xs = (float)x - 255.5f;
    const float ys = (float)y - 255.5f;
    const float xc = (float)(blockIdx.x * 16) + 7.5f - 255.5f;   // block center
    const float yc = (float)(blockIdx.y * 16) + 7.5f - 255.5f;

    // ---- prologue: block-uniform pmin for every angle ----
    for (int a = tid; a < NA; a += 256) {
        const float4 t = tab[a];
        float tc = fmaf(xc, t.x, fmaf(yc, t.y, t.z));
        pm_lds[a] = pmin_of(tc, t.w);
    }
    __syncthreads();

    float acc[NB];
#pragma unroll
    for (int b = 0; b < NB; ++b) acc[b] = 0.0f;

    const uint4* __restrict__ pl2 = st + (size_t)2 * (NA * PS);
    const uint4* __restrict__ pl3 = st + (size_t)3 * (NA * PS);

    // DMA one chunk's 2-plane window into buf[bsel].
    // Slot s = tid + 256*j: al=s>>6, q=(s>>5)&1, pt=s&31 — lane-contiguous
    // within each wave (same pattern as round 10, HW-verified).
    auto issue_dma = [&](int ch, int bsel) {
#pragma unroll
        for (int j = 0; j < 2; ++j) {
            const int s  = tid + 256 * j;
            const int al = s >> 6, q = (s >> 5) & 1, pt = s & 31;
            const int a  = ch * ACH + al;
            const int pm = pm_lds[a];
            const uint4* gp = &st[(size_t)q * (NA * PS) + (size_t)a * PS + pm + pt];
            __builtin_amdgcn_global_load_lds(
                (__attribute__((address_space(1))) const void*)gp,
                (__attribute__((address_space(3))) void*)&buf[bsel][s], 16, 0, 0);
        }
    };

    // flat gather index for the global path
    auto gidx = [&](int a) -> int {
        const float4 t = tab[a];
        float fidx = fmaf(xs, t.x, fmaf(ys, t.y, t.z));
        fidx = fminf(fmaxf(fidx, -1.0f), 512.0f);
        return a * PS + ((int)floorf(fidx) + 1);
    };

    issue_dma(0, 0);
    int iA = gidx(0);
    uint4 gA2 = pl2[iA], gA3 = pl3[iA];         // named regs: no scratch demotion
    int iB = gidx(1);
    uint4 gB2 = pl2[iB], gB3 = pl3[iB];

#pragma unroll 1
    for (int ch = 0; ch < NCH; ++ch) {
        __syncthreads();                        // drains vmcnt: buf[ch&1] ready
        if (ch + 1 < NCH) issue_dma(ch + 1, (ch + 1) & 1);

        const int a0 = ch * ACH;
        const uint4* b = buf[ch & 1];
#pragma unroll
        for (int half = 0; half < ACH / 2; ++half) {
            // ---- even angle: consume prefetch set A ----
            {
                const int a = a0 + 2 * half;
                const float4 t = tab[a];
                float fidx = fmaf(xs, t.x, fmaf(ys, t.y, t.z));
                fidx = fminf(fmaxf(fidx, -1.0f), 512.0f);
                const float fl = floorf(fidx);
                const float w = fidx - fl;
                const half2 wp = u2h(pk(1.0f - w, w));
                const int idx = ((int)fl + 1) - pm_lds[a];
                const uint4 d0 = b[(2 * half) * 64 + idx];
                const uint4 d1 = b[(2 * half) * 64 + 32 + idx];
                acc[0]  = dot2(wp, u2h(d0.x), acc[0]);
                acc[1]  = dot2(wp, u2h(d0.y), acc[1]);
                acc[2]  = dot2(wp, u2h(d0.z), acc[2]);
                acc[3]  = dot2(wp, u2h(d0.w), acc[3]);
                acc[4]  = dot2(wp, u2h(d1.x), acc[4]);
                acc[5]  = dot2(wp, u2h(d1.y), acc[5]);
                acc[6]  = dot2(wp, u2h(d1.z), acc[6]);
                acc[7]  = dot2(wp, u2h(d1.w), acc[7]);
                acc[8]  = dot2(wp, u2h(gA2.x), acc[8]);
                acc[9]  = dot2(wp, u2h(gA2.y), acc[9]);
                acc[10] = dot2(wp, u2h(gA2.z), acc[10]);
                acc[11] = dot2(wp, u2h(gA2.w), acc[11]);
                acc[12] = dot2(wp, u2h(gA3.x), acc[12]);
                acc[13] = dot2(wp, u2h(gA3.y), acc[13]);
                acc[14] = dot2(wp, u2h(gA3.z), acc[14]);
                acc[15] = dot2(wp, u2h(gA3.w), acc[15]);
                const int an = min(a + 2, NA - 1);
                const int i2 = gidx(an);
                gA2 = pl2[i2]; gA3 = pl3[i2];
            }
            // ---- odd angle: consume prefetch set B ----
            {
                const int a = a0 + 2 * half + 1;
                const float4 t = tab[a];
                float fidx = fmaf(xs, t.x, fmaf(ys, t.y, t.z));
                fidx = fminf(fmaxf(fidx, -1.0f), 512.0f);
                const float fl = floorf(fidx);
                const float w = fidx - fl;
                const half2 wp = u2h(pk(1.0f - w, w));
                const int idx = ((int)fl + 1) - pm_lds[a];
                const uint4 d0 = b[(2 * half + 1) * 64 + idx];
                const uint4 d1 = b[(2 * half + 1) * 64 + 32 + idx];
                acc[0]  = dot2(wp, u2h(d0.x), acc[0]);
                acc[1]  = dot2(wp, u2h(d0.y), acc[1]);
                acc[2]  = dot2(wp, u2h(d0.z), acc[2]);
                acc[3]  = dot2(wp, u2h(d0.w), acc[3]);
                acc[4]  = dot2(wp, u2h(d1.x), acc[4]);
                acc[5]  = dot2(wp, u2h(d1.y), acc[5]);
                acc[6]  = dot2(wp, u2h(d1.z), acc[6]);
                acc[7]  = dot2(wp, u2h(d1.w), acc[7]);
                acc[8]  = dot2(wp, u2h(gB2.x), acc[8]);
                acc[9]  = dot2(wp, u2h(gB2.y), acc[9]);
                acc[10] = dot2(wp, u2h(gB2.z), acc[10]);
                acc[11] = dot2(wp, u2h(gB2.w), acc[11]);
                acc[12] = dot2(wp, u2h(gB3.x), acc[12]);
                acc[13] = dot2(wp, u2h(gB3.y), acc[13]);
                acc[14] = dot2(wp, u2h(gB3.z), acc[14]);
                acc[15] = dot2(wp, u2h(gB3.w), acc[15]);
                const int an = min(a + 2, NA - 1);
                const int i2 = gidx(an);
                gB2 = pl2[i2]; gB3 = pl3[i2];
            }
        }
    }

    const size_t pix = (size_t)y * IMG + x;
#pragma unroll
    for (int b = 0; b < NB; ++b)
        out[(size_t)b * (IMG * IMG) + pix] = acc[b];
}

extern "C" void kernel_launch(void* const* d_in, const int* in_sizes, int n_in,
                              void* d_out, int out_size, void* d_ws, size_t ws_size,
                              hipStream_t stream) {
    const float* sino      = (const float*)d_in[0];
    const float* thetas    = (const float*)d_in[1];
    const float* positions = (const float*)d_in[2];
    float* out = (float*)d_out;

    float4* tab = (float4*)d_ws;                     // 360 * 16 B
    uint4*  st  = (uint4*)((char*)d_ws + 8192);      // 4 planes * 2.96 MB = 11.84 MB

    const int nb = (4 * NA * PS + 255) / 256 + 1;    // +1 block computes tab
    stage<<<dim3(nb), dim3(256), 0, stream>>>(sino, thetas, positions, tab, st);
    backproject<<<dim3(IMG / 16, IMG / 16), dim3(16, 16), 0, stream>>>(st, tab, out);
}